// Round 1
// baseline (1936.387 us; speedup 1.0000x reference)
//
#include <hip/hip_runtime.h>

// Problem dims (fixed by setup_inputs): B=2, T=4096, H=16, Dk=Dv=128.
#define B_N   2
#define T_LEN 4096
#define H_N   16
#define D_K   128
#define D_V   128
#define COLS  16   // columns handled per block
#define LPC   16   // lanes per column (one DPP row)
#define EPT   8    // state elements per thread = D_K / LPC

// ---- DPP helpers: sum over a 16-lane row, result broadcast to all 16 lanes.
template <int CTRL>
__device__ __forceinline__ float dpp_add(float x) {
  int y = __builtin_amdgcn_update_dpp(0, __float_as_int(x), CTRL, 0xF, 0xF, true);
  return x + __int_as_float(y);
}

__device__ __forceinline__ float red16(float x) {
  x = dpp_add<0xB1>(x);   // quad_perm [1,0,3,2]  : xor 1
  x = dpp_add<0x4E>(x);   // quad_perm [2,3,0,1]  : xor 2
  x = dpp_add<0x124>(x);  // row_ror:4
  x = dpp_add<0x128>(x);  // row_ror:8
  return x;
}

struct Buf {
  float4 kA, kB, qA, qB;
  float vv, aa, bb;
};

__device__ __forceinline__ void ldbuf(Buf& Bu, const float* __restrict__ kp,
                                      const float* __restrict__ qp,
                                      const float* __restrict__ vp,
                                      const float* __restrict__ ap,
                                      const float* __restrict__ bp, int t) {
  const float* k0 = kp + (size_t)t * (H_N * D_K);
  const float* q0 = qp + (size_t)t * (H_N * D_K);
  Bu.kA = *(const float4*)(k0);
  Bu.kB = *(const float4*)(k0 + 4);
  Bu.qA = *(const float4*)(q0);
  Bu.qB = *(const float4*)(q0 + 4);
  Bu.vv = vp[(size_t)t * (H_N * D_V)];
  Bu.aa = ap[(size_t)t * H_N];
  Bu.bb = bp[(size_t)t * H_N];
}

__device__ __forceinline__ void stepc(const Buf& Bu, float s[EPT], int li,
                                      float* __restrict__ op) {
  float kk[8] = {Bu.kA.x, Bu.kA.y, Bu.kA.z, Bu.kA.w,
                 Bu.kB.x, Bu.kB.y, Bu.kB.z, Bu.kB.w};
  float qq[8] = {Bu.qA.x, Bu.qA.y, Bu.qA.z, Bu.qA.w,
                 Bu.qB.x, Bu.qB.y, Bu.qB.z, Bu.qB.w};
  float pk = 0.f, pu = 0.f, pg = 0.f;
#pragma unroll
  for (int j = 0; j < 8; ++j) {
    pk = fmaf(kk[j], s[j], pk);   // k . s        (old state)
    pu = fmaf(qq[j], s[j], pu);   // q . s        (old state)
    pg = fmaf(kk[j], qq[j], pg);  // k . q
  }
  pk = red16(pk);
  pu = red16(pu);
  pg = red16(pg);
  // S_new[:,v] = a*S[:,v] + k * tmp,  tmp = b*(v - a*(k.S[:,v]))
  float tmp = Bu.bb * (Bu.vv - Bu.aa * pk);
#pragma unroll
  for (int j = 0; j < 8; ++j) s[j] = fmaf(Bu.aa, s[j], kk[j] * tmp);
  // o[v] = q . S_new[:,v] = a*(q.S_old) + (k.q)*tmp
  if (li == 0) *op = fmaf(pg, tmp, Bu.aa * pu);
}

extern "C" __global__ void __launch_bounds__(256) gdn_kernel(
    const float* __restrict__ q, const float* __restrict__ k,
    const float* __restrict__ v, const float* __restrict__ al,
    const float* __restrict__ be, const float* __restrict__ S0,
    float* __restrict__ out) {
  const int G = D_V / COLS;  // 8 column-groups per head
  const int bid = blockIdx.x;
  const int b = bid / (H_N * G);
  const int h = (bid / G) % H_N;
  const int g = bid % G;
  const int tid = threadIdx.x;
  const int cl = tid >> 4;   // column within group
  const int li = tid & 15;   // lane within column (DPP row)
  const int col = g * COLS + cl;
  const int d0 = li * EPT;

  const size_t bh_qk = ((size_t)b * T_LEN * H_N + h) * (size_t)D_K;
  const size_t bh_v = ((size_t)b * T_LEN * H_N + h) * (size_t)D_V;
  const size_t bh_ab = (size_t)b * T_LEN * H_N + h;

  const float* kp = k + bh_qk + d0;
  const float* qp = q + bh_qk + d0;
  const float* vp = v + bh_v + col;
  const float* ap = al + bh_ab;
  const float* bp = be + bh_ab;
  float* op = out + bh_v + col;
  float* sf = out + (size_t)B_N * T_LEN * H_N * D_V +
              ((size_t)(b * H_N + h) * D_K + d0) * (size_t)D_V + col;

  // load initial state: s[j] = S0[b,h,d0+j,col]
  float s[EPT];
  const float* s0p = S0 + ((size_t)(b * H_N + h) * D_K + d0) * (size_t)D_V + col;
#pragma unroll
  for (int j = 0; j < EPT; ++j) s[j] = s0p[(size_t)j * D_V];

  Buf A, Bb;
  ldbuf(A, kp, qp, vp, ap, bp, 0);
  ldbuf(Bb, kp, qp, vp, ap, bp, 1);

  for (int t = 0; t < T_LEN; t += 2) {
    stepc(A, s, li, op + (size_t)t * (H_N * D_V));
    if (t + 2 < T_LEN) ldbuf(A, kp, qp, vp, ap, bp, t + 2);
    stepc(Bb, s, li, op + (size_t)(t + 1) * (H_N * D_V));
    if (t + 3 < T_LEN) ldbuf(Bb, kp, qp, vp, ap, bp, t + 3);
  }

  // final state: S_final[b,h,d,col]
#pragma unroll
  for (int j = 0; j < EPT; ++j) sf[(size_t)j * D_V] = s[j];
}

extern "C" void kernel_launch(void* const* d_in, const int* in_sizes, int n_in,
                              void* d_out, int out_size, void* d_ws,
                              size_t ws_size, hipStream_t stream) {
  const float* q = (const float*)d_in[0];
  const float* k = (const float*)d_in[1];
  const float* v = (const float*)d_in[2];
  const float* al = (const float*)d_in[3];
  const float* be = (const float*)d_in[4];
  const float* S0 = (const float*)d_in[5];
  float* out = (float*)d_out;

  dim3 grid(B_N * H_N * (D_V / COLS));  // 256 blocks: one (b,h,col-group) each
  dim3 block(COLS * LPC);               // 256 threads = 4 waves
  gdn_kernel<<<grid, block, 0, stream>>>(q, k, v, al, be, S0, out);
}

// Round 2
// 1303.613 us; speedup vs baseline: 1.4854x; 1.4854x over previous
//
#include <hip/hip_runtime.h>

// Problem dims (fixed by setup_inputs): B=2, T=4096, H=16, Dk=Dv=128.
#define B_N   2
#define T_LEN 4096
#define H_N   16
#define D_K   128
#define D_V   128
#define COLS  16   // columns handled per block
#define LPC   16   // lanes per column (one DPP row)
#define EPT   8    // state elements per thread = D_K / LPC
#define PF    8    // prefetch pipeline depth (steps ahead)

// ---- DPP helpers: sum over a 16-lane row, result broadcast to all 16 lanes.
template <int CTRL>
__device__ __forceinline__ float dpp_add(float x) {
  int y = __builtin_amdgcn_update_dpp(0, __float_as_int(x), CTRL, 0xF, 0xF, true);
  return x + __int_as_float(y);
}

__device__ __forceinline__ float red16(float x) {
  x = dpp_add<0xB1>(x);   // quad_perm [1,0,3,2]  : xor 1
  x = dpp_add<0x4E>(x);   // quad_perm [2,3,0,1]  : xor 2
  x = dpp_add<0x124>(x);  // row_ror:4
  x = dpp_add<0x128>(x);  // row_ror:8
  return x;
}

struct Buf {
  float4 kA, kB, qA, qB;
  float vv, aa, bb;
};

__device__ __forceinline__ void ldbuf(Buf& Bu, const float* __restrict__ kp,
                                      const float* __restrict__ qp,
                                      const float* __restrict__ vp,
                                      const float* __restrict__ ap,
                                      const float* __restrict__ bp, int t) {
  const float* k0 = kp + (size_t)t * (H_N * D_K);
  const float* q0 = qp + (size_t)t * (H_N * D_K);
  Bu.kA = *(const float4*)(k0);
  Bu.kB = *(const float4*)(k0 + 4);
  Bu.qA = *(const float4*)(q0);
  Bu.qB = *(const float4*)(q0 + 4);
  Bu.vv = vp[(size_t)t * (H_N * D_V)];
  Bu.aa = ap[(size_t)t * H_N];
  Bu.bb = bp[(size_t)t * H_N];
}

__device__ __forceinline__ void stepc(const Buf& Bu, float s[EPT], int li,
                                      float* __restrict__ op) {
  float kk[8] = {Bu.kA.x, Bu.kA.y, Bu.kA.z, Bu.kA.w,
                 Bu.kB.x, Bu.kB.y, Bu.kB.z, Bu.kB.w};
  float qq[8] = {Bu.qA.x, Bu.qA.y, Bu.qA.z, Bu.qA.w,
                 Bu.qB.x, Bu.qB.y, Bu.qB.z, Bu.qB.w};
  // Split each dot into 2 accumulators to shorten the serial FMA chain.
  float pk0 = 0.f, pk1 = 0.f, pu0 = 0.f, pu1 = 0.f, pg0 = 0.f, pg1 = 0.f;
#pragma unroll
  for (int j = 0; j < 4; ++j) {
    pk0 = fmaf(kk[j], s[j], pk0);
    pk1 = fmaf(kk[j + 4], s[j + 4], pk1);
    pu0 = fmaf(qq[j], s[j], pu0);
    pu1 = fmaf(qq[j + 4], s[j + 4], pu1);
    pg0 = fmaf(kk[j], qq[j], pg0);   // k.q — off the state-dependent path
    pg1 = fmaf(kk[j + 4], qq[j + 4], pg1);
  }
  float pk = red16(pk0 + pk1);
  float pu = red16(pu0 + pu1);
  float pg = red16(pg0 + pg1);
  // S_new[:,v] = a*S[:,v] + k * tmp,  tmp = b*(v - a*(k.S[:,v]))
  float tmp = Bu.bb * (Bu.vv - Bu.aa * pk);
#pragma unroll
  for (int j = 0; j < 8; ++j) s[j] = fmaf(Bu.aa, s[j], kk[j] * tmp);
  // o[v] = q . S_new[:,v] = a*(q.S_old) + (k.q)*tmp
  if (li == 0) *op = fmaf(pg, tmp, Bu.aa * pu);
}

extern "C" __global__ void __launch_bounds__(256, 1) gdn_kernel(
    const float* __restrict__ q, const float* __restrict__ k,
    const float* __restrict__ v, const float* __restrict__ al,
    const float* __restrict__ be, const float* __restrict__ S0,
    float* __restrict__ out) {
  // XCD-affinity decode: all 8 column-group blocks of one (b,h) share
  // (blockIdx mod 8) -> same XCD under round-robin dispatch -> k/q re-reads
  // hit that XCD's L2 instead of HBM.
  const int bid = blockIdx.x;
  const int bh = bid & 31;   // (b,h) combo: 32 of them
  const int g = bid >> 5;    // column group 0..7
  const int b = bh >> 4;
  const int h = bh & 15;
  const int tid = threadIdx.x;
  const int cl = tid >> 4;   // column within group
  const int li = tid & 15;   // lane within column (DPP row)
  const int col = g * COLS + cl;
  const int d0 = li * EPT;

  const size_t bh_qk = ((size_t)b * T_LEN * H_N + h) * (size_t)D_K;
  const size_t bh_v = ((size_t)b * T_LEN * H_N + h) * (size_t)D_V;
  const size_t bh_ab = (size_t)b * T_LEN * H_N + h;

  const float* kp = k + bh_qk + d0;
  const float* qp = q + bh_qk + d0;
  const float* vp = v + bh_v + col;
  const float* ap = al + bh_ab;
  const float* bp = be + bh_ab;
  float* op = out + bh_v + col;
  float* sf = out + (size_t)B_N * T_LEN * H_N * D_V +
              ((size_t)(b * H_N + h) * D_K + d0) * (size_t)D_V + col;

  // load initial state: s[j] = S0[b,h,d0+j,col]
  float s[EPT];
  const float* s0p = S0 + ((size_t)(b * H_N + h) * D_K + d0) * (size_t)D_V + col;
#pragma unroll
  for (int j = 0; j < EPT; ++j) s[j] = s0p[(size_t)j * D_V];

  // 8-deep prefetch ring: loads issue PF steps (~8 * step-time) before use.
  Buf buf[PF];
#pragma unroll
  for (int i = 0; i < PF; ++i) ldbuf(buf[i], kp, qp, vp, ap, bp, i);

  for (int t = 0; t < T_LEN; t += PF) {
#pragma unroll
    for (int i = 0; i < PF; ++i) {
      stepc(buf[i], s, li, op + (size_t)(t + i) * (H_N * D_V));
      const int tn = t + i + PF;
      if (tn < T_LEN) ldbuf(buf[i], kp, qp, vp, ap, bp, tn);
    }
  }

  // final state: S_final[b,h,d,col]
#pragma unroll
  for (int j = 0; j < EPT; ++j) sf[(size_t)j * D_V] = s[j];
}

extern "C" void kernel_launch(void* const* d_in, const int* in_sizes, int n_in,
                              void* d_out, int out_size, void* d_ws,
                              size_t ws_size, hipStream_t stream) {
  const float* q = (const float*)d_in[0];
  const float* k = (const float*)d_in[1];
  const float* v = (const float*)d_in[2];
  const float* al = (const float*)d_in[3];
  const float* be = (const float*)d_in[4];
  const float* S0 = (const float*)d_in[5];
  float* out = (float*)d_out;

  dim3 grid(B_N * H_N * (D_V / COLS));  // 256 blocks: one (b,h,col-group) each
  dim3 block(COLS * LPC);               // 256 threads = 4 waves
  gdn_kernel<<<grid, block, 0, stream>>>(q, k, v, al, be, S0, out);
}